// Round 6
// baseline (102.678 us; speedup 1.0000x reference)
//
#include <hip/hip_runtime.h>
#include <math.h>

#define BB 64
#define DD 512
#define HH 8
#define EPS 1e-8f
#define CAP 64          // window-length cap for the peaked queue
#define TDROP 16.0f     // keep r > m - 16: dropped mass < 512*e^-16 ~ 5.7e-5 vs ss>=1

// Cross-kernel buffers (avoids d_ws size assumptions; legal under graph capture).
__device__ float g_xsorted[BB][DD];
__device__ int   g_perm[BB][DD];

// Raw v_rcp_f32 (~1 ulp). ml and the loop's rr at the argmin come from the
// IDENTICAL instruction chain on identical bits -> rr - ml == 0 exactly at the
// argmin -> s = exp2(0) = 1, no overflow, for arbitrarily large m.
__device__ __forceinline__ float fast_rcp(float d) {
    return __builtin_amdgcn_rcpf(d);
}

// ---------------- kernel 1: per-b rank-counting sort (1 barrier) -------------
// rank(i) = #{j : x_j < x_i or (x_j == x_i and j < i)} -> stable permutation.
// Also zeroes `out` (stream-ordered before flattn's atomics) -> no memset.
__global__ __launch_bounds__(DD) void sort_kernel(const float* __restrict__ x,
                                                  float* __restrict__ out)
{
    const int b   = blockIdx.x;
    const int tid = threadIdx.x;
    __shared__ float sv[DD];
    const float xi = x[b * DD + tid];
    sv[tid] = xi;
    out[b * DD + tid] = 0.0f;
    __syncthreads();

    int cnt = 0;
    #pragma unroll 4
    for (int j = 0; j < DD; j += 4) {
        float4 v = *(const float4*)&sv[j];
        cnt += (int)((v.x < xi) | ((v.x == xi) & ((j + 0) < tid)));
        cnt += (int)((v.y < xi) | ((v.y == xi) & ((j + 1) < tid)));
        cnt += (int)((v.z < xi) | ((v.z == xi) & ((j + 2) < tid)));
        cnt += (int)((v.w < xi) | ((v.w == xi) & ((j + 3) < tid)));
    }
    g_xsorted[b][cnt] = xi;
    g_perm[b][cnt]    = tid;
}

// ---------------- kernel 2: attention with REGIME COMPACTION -----------------
// Per-lane prelude gives the EXACT softmax max (V-shape: argmin in {pos-1,pos})
// and a covering window. Lanes are then reshuffled through two LDS queues
// (peaked: window<=CAP; flat: rest) so each wave is regime-homogeneous:
//   peaked waves: trip = wave-max window half (<=32), per-lane LDS gather
//   flat waves:   full 512-term sum, every lane doing necessary work
// At most one straddle wave per block pays both. Wave-uniform gates can no
// longer be poisoned by mixed lanes (the r1/r4/r5 failure mode).
__global__ __launch_bounds__(512, 8) void flattn_kernel(
    const float* __restrict__ x,
    const float* __restrict__ alphas,
    const float* __restrict__ betas,
    float* __restrict__ out)
{
    const int b  = blockIdx.x;
    const int ic = blockIdx.y;
    const int h  = blockIdx.z;

    __shared__ float xs[DD];       // original order (flat path, float4 broadcast)
    __shared__ float xss[DD];      // sorted order  (prelude + peaked gather)
    __shared__ float ss_sh[256];
    __shared__ float sx_sh[256];
    __shared__ float c_sh[256];    // per-i meta, indexed by ii (rank within ic)
    __shared__ float ml_sh[256];
    __shared__ int   lohi_sh[256]; // lo | hi<<16
    __shared__ int   q_sh[256];    // [0,nP): peaked entries; [nP,256): flat
    __shared__ int   cnt_sh[2];

    const int tid = threadIdx.x;
    const int ii  = tid & 255;
    const int jc  = tid >> 8;      // wave-uniform; waves (w, w+4) pair up

    const float a0 = alphas[h * 3 + 0];   // block-uniform
    const float a1 = alphas[h * 3 + 1];
    const float a2 = alphas[h * 3 + 2];
    const float b0 = betas[h * 3 + 0];
    const float b1 = betas[h * 3 + 1];
    const float b2 = betas[h * 3 + 2];

    xs[tid]  = x[b * DD + tid];
    xss[tid] = g_xsorted[b][tid];
    if (tid < 2) cnt_sh[tid] = 0;
    __syncthreads();

    const float LN2    = 0.6931471805599453f;
    const float EPSLN2 = 6.931471805599453e-9f;   // EPS*ln2

    // ---- prelude + classification: jc==0 threads only (wave-uniform skip) --
    if (jc == 0) {
        const int rank = ic * 256 + ii;
        const float xi = xss[rank];               // bitwise x[perm[rank]]
        const float c  = b0 - fmaf(a1, xi, b1);   // t_j = a0*x_j + c

        const float ra0 = fast_rcp(a0);
        float u = -c * ra0;                       // |t| minimized at x ~= u
        if (!(u == u)) u = 0.0f;                  // a0==0 && c==0 belt (NaN)

        int pos = 0;                              // count of sorted elems < u
        #pragma unroll
        for (int s = 512; s > 0; s >>= 1) {
            int p = pos + s;
            float v = xss[(p <= 512 ? p : 512) - 1];
            pos = (p <= 512 && v < u) ? p : pos;
        }
        float mind_hat = 3.0e38f;                 // EXACT global min of |t|
        #pragma unroll
        for (int q = -2; q <= 1; ++q) {
            int ci = pos + q;
            if (ci >= 0 && ci < DD)
                mind_hat = fminf(mind_hat, fabsf(fmaf(a0, xss[ci], c)));
        }
        // ml = m*log2e via the same chain the loops use -> exact cancellation
        const float ml    = fast_rcp(fmaf(mind_hat, LN2, EPSLN2));
        const float m_nat = fast_rcp(mind_hat + EPS);

        // covering window: all x with |t| < 1/(m-16) (+slack, +-2 rank widen)
        const float th  = fast_rcp(fmaxf(m_nat - TDROP, 1e-30f));
        const float tha = fmaf(th * 1.001f, ra0, 1e-6f);
        const float xlo = u - tha;
        const float xhi = u + tha;

        int l = 0, hc = 0;         // l = count(< xlo), hc = count(<= xhi)
        #pragma unroll
        for (int s = 512; s > 0; s >>= 1) {
            int pl = l + s, ph = hc + s;
            float vl = xss[(pl <= 512 ? pl : 512) - 1];
            float vh = xss[(ph <= 512 ? ph : 512) - 1];
            l  = (pl <= 512 && vl <  xlo) ? pl : l;
            hc = (ph <= 512 && vh <= xhi) ? ph : hc;
        }
        const int lo = max(l - 2, 0);
        const int hi = min(hc + 2, DD);

        c_sh[ii]    = c;
        ml_sh[ii]   = ml;
        lohi_sh[ii] = lo | (hi << 16);
        if (hi - lo <= CAP) {
            int p = atomicAdd(&cnt_sh[0], 1);
            q_sh[p] = ii;                         // peaked queue grows up
        } else {
            int p = atomicAdd(&cnt_sh[1], 1);
            q_sh[255 - p] = ii;                   // flat queue grows down
        }
    }
    __syncthreads();

    // ---- process queue entry e = q[ii] (jc halves split the j-work) --------
    const int   nP    = cnt_sh[0];
    const int   e     = q_sh[ii];
    const int   meta  = lohi_sh[e];
    const int   elo   = meta & 0xffff;
    const int   ehi   = meta >> 16;
    const float ce    = c_sh[e];
    const float mle   = ml_sh[e];
    const bool  isflat = (ii >= nP);              // class == queue position

    float ss = 0.0f, sx = 0.0f;

    // peaked: iterate own window half; trip = wave-max (<= CAP/2 = 32)
    {
        const int mylen = isflat ? 0 : (ehi - elo);
        const int half1 = (mylen + 1) >> 1;
        const int wl    = elo + (jc ? half1 : 0);
        const int wn    = jc ? (mylen - half1) : half1;
        int T = wn;
        #pragma unroll
        for (int msk = 1; msk < 64; msk <<= 1)
            T = max(T, __shfl_xor(T, msk, 64));
        for (int k = 0; k < T; ++k) {
            const bool  valid = (k < wn);
            const float xv = xss[min(wl + k, DD - 1)];
            const float t  = fmaf(a0, xv, ce);
            const float w  = fmaf(fabsf(t), LN2, EPSLN2);
            float s = __builtin_amdgcn_exp2f(fast_rcp(w) - mle);
            s = valid ? s : 0.0f;
            ss += s;
            sx = fmaf(s, xv, sx);
        }
    }

    // flat: full sum over this jc-half (uniform float4 broadcast from xs).
    // Straddle-wave peaked lanes get mlf=+inf -> s = exp2(-inf) = 0 (free).
    if (__any(isflat)) {
        const float mlf = isflat ? mle : __builtin_inff();
        const int j0 = jc * 256;
        #pragma unroll 2
        for (int j = j0; j < j0 + 256; j += 4) {
            float4 x4 = *(const float4*)&xs[j];
            {
                float t = fmaf(a0, x4.x, ce);
                float s = __builtin_amdgcn_exp2f(fast_rcp(fmaf(fabsf(t), LN2, EPSLN2)) - mlf);
                ss += s; sx = fmaf(s, x4.x, sx);
            }
            {
                float t = fmaf(a0, x4.y, ce);
                float s = __builtin_amdgcn_exp2f(fast_rcp(fmaf(fabsf(t), LN2, EPSLN2)) - mlf);
                ss += s; sx = fmaf(s, x4.y, sx);
            }
            {
                float t = fmaf(a0, x4.z, ce);
                float s = __builtin_amdgcn_exp2f(fast_rcp(fmaf(fabsf(t), LN2, EPSLN2)) - mlf);
                ss += s; sx = fmaf(s, x4.z, sx);
            }
            {
                float t = fmaf(a0, x4.w, ce);
                float s = __builtin_amdgcn_exp2f(fast_rcp(fmaf(fabsf(t), LN2, EPSLN2)) - mlf);
                ss += s; sx = fmaf(s, x4.w, sx);
            }
        }
    }

    // ---- merge jc-halves, one atomic per (i, h) ----------------------------
    if (jc == 1) { ss_sh[ii] = ss; sx_sh[ii] = sx; }
    __syncthreads();
    if (jc == 0) {
        ss += ss_sh[ii];
        sx += sx_sh[ii];
        const float scale = 0.04419417382415922f;   // 1/sqrt(512)
        float sv  = fmaf(a2, sx, b2 * ss);
        float att = sv * fast_rcp(ss) * scale;      // ss >= 1 (argmin term = 1)
        const int rank_e = ic * 256 + e;
        if (h == 0) att += xss[rank_e];
        atomicAdd(&out[b * DD + g_perm[b][rank_e]], att);
    }
}

extern "C" void kernel_launch(void* const* d_in, const int* in_sizes, int n_in,
                              void* d_out, int out_size, void* d_ws, size_t ws_size,
                              hipStream_t stream) {
    const float* x      = (const float*)d_in[0];
    const float* alphas = (const float*)d_in[1];
    const float* betas  = (const float*)d_in[2];
    float* out = (float*)d_out;

    sort_kernel<<<dim3(BB), dim3(DD), 0, stream>>>(x, out);

    dim3 grid(BB, 2, HH);
    dim3 block(512);
    flattn_kernel<<<grid, block, 0, stream>>>(x, alphas, betas, out);
}

// Round 7
// 95.004 us; speedup vs baseline: 1.0808x; 1.0808x over previous
//
#include <hip/hip_runtime.h>
#include <math.h>

#define BB 64
#define DD 512
#define HH 8
#define EPS 1e-8f
#define CAP 64          // window-length cap for the peaked class
#define TDROP 16.0f     // keep r > m - 16: dropped mass < 512*e^-16 ~ 5.7e-5 vs ss>=1

// Cross-kernel buffers (avoids d_ws size assumptions; legal under graph capture).
__device__ float g_xsorted[BB][DD];
__device__ int   g_perm[BB][DD];

// Raw v_rcp_f32 (~1 ulp). ml and the loops' per-j value at the argmin come from
// the IDENTICAL instruction chain on identical bits -> exp2(0)=1 exactly at the
// argmin -> no overflow for arbitrarily large m, and ss >= 1 always.
__device__ __forceinline__ float fast_rcp(float d) {
    return __builtin_amdgcn_rcpf(d);
}

// ---------------- kernel 1: per-b rank-counting sort (1 barrier) -------------
__global__ __launch_bounds__(DD) void sort_kernel(const float* __restrict__ x,
                                                  float* __restrict__ out)
{
    const int b   = blockIdx.x;
    const int tid = threadIdx.x;
    __shared__ float sv[DD];
    const float xi = x[b * DD + tid];
    sv[tid] = xi;
    out[b * DD + tid] = 0.0f;
    __syncthreads();

    int cnt = 0;
    #pragma unroll 4
    for (int j = 0; j < DD; j += 4) {
        float4 v = *(const float4*)&sv[j];
        cnt += (int)((v.x < xi) | ((v.x == xi) & ((j + 0) < tid)));
        cnt += (int)((v.y < xi) | ((v.y == xi) & ((j + 1) < tid)));
        cnt += (int)((v.z < xi) | ((v.z == xi) & ((j + 2) < tid)));
        cnt += (int)((v.w < xi) | ((v.w == xi) & ((j + 3) < tid)));
    }
    g_xsorted[b][cnt] = xi;
    g_perm[b][cnt]    = tid;
}

// ---------------- kernel 2: attention, compaction + COOPERATIVE flat phase ---
// Phase A: peaked entries (window<=CAP), entry e=q[ii], jc halves split window.
// Phase B: flat entries processed one-per-WAVE (64 lanes x 8 j's, shfl reduce):
//          flat work per thread ~ nF elems instead of 256 serial -> kills the
//          per-block tail that nulled r4/r5/r6.
__global__ __launch_bounds__(512, 8) void flattn_kernel(
    const float* __restrict__ alphas,
    const float* __restrict__ betas,
    float* __restrict__ out)
{
    const int b  = blockIdx.x;
    const int ic = blockIdx.y;
    const int h  = blockIdx.z;

    __shared__ float xss[DD];      // sorted order (prelude, gathers, flat sweep)
    __shared__ float c_sh[256];    // per-entry meta, indexed by entry ii
    __shared__ float ml_sh[256];   // m * log2e (exact, same-chain)
    __shared__ int   lohi_sh[256]; // lo | hi<<16
    __shared__ int   q_sh[256];    // [0,nP): peaked; flat at 255,254,...
    __shared__ float fs_sh[256];   // final ss per entry
    __shared__ float fx_sh[256];   // final sx per entry
    __shared__ float ssB_sh[256];  // phase-A jc=1 partials
    __shared__ float sxB_sh[256];
    __shared__ int   cnt_sh[2];

    const int tid = threadIdx.x;
    const int ii  = tid & 255;
    const int jc  = tid >> 8;      // wave-uniform; waves (w, w+4) pair up

    const float a0 = alphas[h * 3 + 0];   // block-uniform
    const float a1 = alphas[h * 3 + 1];
    const float a2 = alphas[h * 3 + 2];
    const float b0 = betas[h * 3 + 0];
    const float b1 = betas[h * 3 + 1];
    const float b2 = betas[h * 3 + 2];

    xss[tid] = g_xsorted[b][tid];
    if (tid < 2) cnt_sh[tid] = 0;
    __syncthreads();

    const float LN2    = 0.6931471805599453f;
    const float EPSLN2 = 6.931471805599453e-9f;   // EPS*ln2

    // ---- prelude + classification (jc==0 threads; one entry each) ----------
    if (jc == 0) {
        const int rank = ic * 256 + ii;
        const float xi = xss[rank];
        const float c  = b0 - fmaf(a1, xi, b1);   // t_j = a0*x_j + c

        const float ra0 = fast_rcp(a0);
        float u = -c * ra0;
        if (!(u == u)) u = 0.0f;

        int pos = 0;                              // count of sorted elems < u
        #pragma unroll
        for (int s = 512; s > 0; s >>= 1) {
            int p = pos + s;
            float v = xss[(p <= 512 ? p : 512) - 1];
            pos = (p <= 512 && v < u) ? p : pos;
        }
        float mind_hat = 3.0e38f;                 // EXACT global min (V-shape)
        #pragma unroll
        for (int q = -2; q <= 1; ++q) {
            int ci = pos + q;
            if (ci >= 0 && ci < DD)
                mind_hat = fminf(mind_hat, fabsf(fmaf(a0, xss[ci], c)));
        }
        const float ml    = fast_rcp(fmaf(mind_hat, LN2, EPSLN2));
        const float m_nat = fast_rcp(mind_hat + EPS);

        const float th  = fast_rcp(fmaxf(m_nat - TDROP, 1e-30f));
        const float tha = fmaf(th * 1.001f, ra0, 1e-6f);
        const float xlo = u - tha;
        const float xhi = u + tha;

        int l = 0, hc = 0;
        #pragma unroll
        for (int s = 512; s > 0; s >>= 1) {
            int pl = l + s, ph = hc + s;
            float vl = xss[(pl <= 512 ? pl : 512) - 1];
            float vh = xss[(ph <= 512 ? ph : 512) - 1];
            l  = (pl <= 512 && vl <  xlo) ? pl : l;
            hc = (ph <= 512 && vh <= xhi) ? ph : hc;
        }
        const int lo = max(l - 2, 0);
        const int hi = min(hc + 2, DD);

        c_sh[ii]    = c;
        ml_sh[ii]   = ml;
        lohi_sh[ii] = lo | (hi << 16);
        if (hi - lo <= CAP) {
            int p = atomicAdd(&cnt_sh[0], 1);
            q_sh[p] = ii;                         // peaked queue grows up
        } else {
            int p = atomicAdd(&cnt_sh[1], 1);
            q_sh[255 - p] = ii;                   // flat queue grows down
        }
    }
    __syncthreads();

    const int nP = cnt_sh[0];
    const int nF = 256 - nP;

    // ---- Phase A: peaked entries, e = q[ii], jc halves split the window ----
    {
        const int   e     = q_sh[ii];
        const bool  mine  = (ii < nP);
        const int   meta  = lohi_sh[e];
        const int   elo   = meta & 0xffff;
        const int   ehi   = meta >> 16;
        const float ce    = c_sh[e];
        const float mle   = ml_sh[e];

        const int mylen = mine ? (ehi - elo) : 0;
        const int half1 = (mylen + 1) >> 1;
        const int wl    = elo + (jc ? half1 : 0);
        const int wn    = jc ? (mylen - half1) : half1;
        int T = wn;
        #pragma unroll
        for (int msk = 1; msk < 64; msk <<= 1)
            T = max(T, __shfl_xor(T, msk, 64));

        float ss = 0.0f, sx = 0.0f;
        for (int k = 0; k < T; ++k) {           // T<=32; all-flat waves: T=0
            const bool  valid = (k < wn);
            const float xv = xss[min(wl + k, DD - 1)];
            const float t  = fmaf(a0, xv, ce);
            const float w  = fmaf(fabsf(t), LN2, EPSLN2);
            float s = __builtin_amdgcn_exp2f(fast_rcp(w) - mle);
            s = valid ? s : 0.0f;
            ss += s;
            sx = fmaf(s, xv, sx);
        }
        if (jc == 1) { ssB_sh[ii] = ss; sxB_sh[ii] = sx; }
        __syncthreads();
        if (jc == 0 && mine) {
            fs_sh[e] = ss + ssB_sh[ii];
            fx_sh[e] = sx + sxB_sh[ii];
        }
    }

    // ---- Phase B: flat entries, one per WAVE (64 lanes x 8 j, shfl reduce) --
    {
        const int w    = tid >> 6;              // wave id 0..7
        const int lane = tid & 63;
        const int ns   = (nF + 7) >> 3;         // sweeps of 8 entries
        for (int s = 0; s < ns; ++s) {
            const int fidx = s * 8 + w;
            if (fidx < nF) {
                const int   e   = q_sh[255 - fidx];
                const float ce  = c_sh[e];
                const float mle = ml_sh[e];
                float fss = 0.0f, fsx = 0.0f;
                #pragma unroll
                for (int kk = 0; kk < 8; ++kk) {    // stride-64: conflict-free
                    const float xv = xss[lane + (kk << 6)];
                    const float t  = fmaf(a0, xv, ce);
                    const float wv = fmaf(fabsf(t), LN2, EPSLN2);
                    const float sv = __builtin_amdgcn_exp2f(fast_rcp(wv) - mle);
                    fss += sv;
                    fsx = fmaf(sv, xv, fsx);
                }
                #pragma unroll
                for (int msk = 1; msk < 64; msk <<= 1) {
                    fss += __shfl_xor(fss, msk, 64);
                    fsx += __shfl_xor(fsx, msk, 64);
                }
                if (lane == 0) { fs_sh[e] = fss; fx_sh[e] = fsx; }
            }
        }
    }
    __syncthreads();

    // ---- epilogue: one thread per entry, one atomic per (i, h) -------------
    if (tid < 256) {
        const float ss = fs_sh[tid];
        const float sx = fx_sh[tid];
        const float scale = 0.04419417382415922f;   // 1/sqrt(512)
        float sv  = fmaf(a2, sx, b2 * ss);
        float att = sv * fast_rcp(ss) * scale;      // ss >= 1 (argmin term = 1)
        const int rank = ic * 256 + tid;
        if (h == 0) att += xss[rank];
        atomicAdd(&out[b * DD + g_perm[b][rank]], att);
    }
}

extern "C" void kernel_launch(void* const* d_in, const int* in_sizes, int n_in,
                              void* d_out, int out_size, void* d_ws, size_t ws_size,
                              hipStream_t stream) {
    const float* x      = (const float*)d_in[0];
    const float* alphas = (const float*)d_in[1];
    const float* betas  = (const float*)d_in[2];
    float* out = (float*)d_out;

    sort_kernel<<<dim3(BB), dim3(DD), 0, stream>>>(x, out);

    dim3 grid(BB, 2, HH);
    dim3 block(512);
    flattn_kernel<<<grid, block, 0, stream>>>(alphas, betas, out);
}